// Round 12
// baseline (1028.302 us; speedup 1.0000x reference)
//
#include <hip/hip_runtime.h>
#include <hip/hip_fp16.h>

#define NA 100000
#define NB 200000
#define MAXNB 6
#define AF 133
#define BF 147
#define H 300
#define HP 320     // padded fp16 row width for msg/amsg/inp (640B)
#define AFP 160    // padded fp16 row width for f_bonds/f_atoms
#define NP 320     // weight N padding = BN
#define BM 128
#define BN 320
#define BK 32
#define NTH 512
#define LDK 40     // LDS row stride (32 + 8 pad)

typedef _Float16 f16;
typedef __attribute__((ext_vector_type(8))) _Float16 f16x8;
typedef __attribute__((ext_vector_type(4))) float f32x4;

// ---- fp32 [M][Ks] -> fp16 [M][160] zero-padded ----------------------------
__global__ void conv_pad_f16(const float* __restrict__ src, f16* __restrict__ dst,
                             int M, int Ks) {
  int idx = blockIdx.x * blockDim.x + threadIdx.x;
  if (idx >= M * (AFP / 8)) return;
  int r = idx / (AFP / 8);
  int c = (idx - r * (AFP / 8)) * 8;
  f16x8 o;
#pragma unroll
  for (int j = 0; j < 8; ++j) {
    int k = c + j;
    o[j] = (k < Ks) ? (f16)src[(size_t)r * Ks + k] : (f16)0.0f;
  }
  *(f16x8*)&dst[(size_t)r * AFP + c] = o;
}

// ---- W_i -> [n][160] fp16 --------------------------------------------------
__global__ void prep_wi(const float* __restrict__ Wi, f16* __restrict__ dst) {
  int idx = blockIdx.x * blockDim.x + threadIdx.x;
  if (idx >= NP * 160) return;
  int n = idx / 160, k = idx - n * 160;
  float v = (n < H && k < BF) ? Wi[(size_t)k * H + n] : 0.0f;
  dst[idx] = (f16)v;
}

// ---- W_h -> [n][320] fp16 --------------------------------------------------
__global__ void prep_wh(const float* __restrict__ Wh, f16* __restrict__ dst) {
  int idx = blockIdx.x * blockDim.x + threadIdx.x;
  if (idx >= NP * 320) return;
  int n = idx / 320, k = idx - n * 320;
  float v = (n < H && k < H) ? Wh[(size_t)k * H + n] : 0.0f;
  dst[idx] = (f16)v;
}

// ---- W_o remapped for [f_atoms(133->160 pad), amsg(300->320 pad)] ----------
__global__ void prep_wo(const float* __restrict__ src, f16* __restrict__ dst) {
  int idx = blockIdx.x * blockDim.x + threadIdx.x;
  if (idx >= NP * 480) return;
  int n = idx / 480, k = idx - n * 480;
  int ks = -1;
  if (k < AF) ks = k;
  else if (k >= AFP && k < AFP + H) ks = AF + (k - AFP);
  float v = (n < H && ks >= 0) ? src[(size_t)ks * H + n] : 0.0f;
  dst[idx] = (f16)v;
}

// ---- a_msg[a][:] = sum_t msg[a2b[a][t]][:] --------------------------------
__global__ void gather_sum_kernel(const f16* __restrict__ msg,
                                  const int* __restrict__ a2b,
                                  f16* __restrict__ amsg) {
  int idx = blockIdx.x * blockDim.x + threadIdx.x;
  if (idx >= NA * (HP / 8)) return;
  int a = idx / (HP / 8);
  int c = (idx - a * (HP / 8)) * 8;
  const int* nbr = &a2b[(size_t)a * MAXNB];
  float acc[8] = {0.f, 0.f, 0.f, 0.f, 0.f, 0.f, 0.f, 0.f};
#pragma unroll
  for (int t = 0; t < MAXNB; ++t) {
    int r = nbr[t];
    f16x8 v = *(const f16x8*)&msg[(size_t)r * HP + c];
#pragma unroll
    for (int j = 0; j < 8; ++j) acc[j] += (float)v[j];
  }
  f16x8 o;
#pragma unroll
  for (int j = 0; j < 8; ++j) o[j] = (f16)acc[j];
  *(f16x8*)&amsg[(size_t)a * HP + c] = o;
}

// ---- unified GEMM: 128x320 tile, 8 waves (2x4), BK=32, dbuf LDS -----------
// ONE barrier per k-step; loads issued ~1.5 iterations before consumption.
// MODE 0: inp = fb16 @ W_i ; msg = relu(inp)                    (K=160)
// MODE 1: msg' = relu(inp + (amsg[b2a]-msg[b2revb]) @ W_h)      (K=320)
// MODE 2: out = relu([fa16, amsg(dense)] @ W_o + b_o)           (K=480)
template <int MODE>
__global__ __launch_bounds__(NTH)
void gemm_kernel(const f16* __restrict__ Afp,    // fb16 (MODE 0) / fa16 (MODE 2)
                 const f16* __restrict__ amsg,   // MODE1: gathered; MODE2: dense
                 const f16* __restrict__ msg_in, // MODE1 only
                 const int* __restrict__ b2a,
                 const int* __restrict__ b2revb,
                 const f16* __restrict__ Wp,
                 const f16* __restrict__ inp_r,  // MODE1 epilogue skip-add
                 const float* __restrict__ b_o,
                 f16* __restrict__ out_inp,      // MODE0 only
                 f16* __restrict__ out_msg,
                 float* __restrict__ out_f32) {
  constexpr int KP = (MODE == 0) ? 160 : (MODE == 1) ? 320 : 480;
  constexpr int KSTEPS = KP / BK;
  constexpr int ASTEPS = 5;                // MODE2: k-steps sourced from fa16
  constexpr int M = (MODE == 2) ? NA : NB;

  __shared__ f16 As[2][BM][LDK];
  __shared__ f16 Bs[2][BN][LDK];

  const int mb = blockIdx.x;
  const int tid = threadIdx.x;
  const int lane = tid & 63, wid = tid >> 6;
  const int wr = wid >> 2, wc = wid & 3;   // 2 x 4 wave grid

  f32x4 acc[4][5] = {};

  // A staging: 512 8-elem chunks == NTH; thread -> (tid>>2, (tid&3)*8)
  const int arow = tid >> 2;
  const int ac = (tid & 3) * 8;
  const int m_g = mb * BM + arow;
  const int mrow = (m_g < M) ? m_g : 0;  // clamp: OOB rows masked in epilogue

  // B staging: 1280 chunks over 512 threads (3rd chunk partial, tid<256)
  const int bidx2 = tid + 2 * NTH;
  const int br0 = tid >> 2,            bc0 = (tid & 3) * 8;
  const int br1 = (tid + NTH) >> 2,    bc1 = ((tid + NTH) & 3) * 8;
  const int br2 = bidx2 >> 2,          bc2 = (bidx2 & 3) * 8;
  const bool b2ok = bidx2 < BN * 4;

  int ra = 0, rb = 0;
  if constexpr (MODE == 1) { ra = b2a[mrow]; rb = b2revb[mrow]; }

  // single staging set: live only from issue to the following write_lds
  f16x8 ax, ay, pw0, pw1, pw2;

  auto issue_loads = [&](int ks) {
    const int kb = ks * BK + ac;
    if constexpr (MODE == 0) {
      ax = *(const f16x8*)&Afp[(size_t)mrow * AFP + kb];
    } else if constexpr (MODE == 1) {
      ax = *(const f16x8*)&amsg[(size_t)ra * HP + kb];
      ay = *(const f16x8*)&msg_in[(size_t)rb * HP + kb];
    } else {
      ax = (ks < ASTEPS) ? *(const f16x8*)&Afp[(size_t)mrow * AFP + kb]
                         : *(const f16x8*)&amsg[(size_t)mrow * HP + (kb - AFP)];
    }
    const int kw = ks * BK;
    pw0 = *(const f16x8*)&Wp[(size_t)br0 * KP + kw + bc0];
    pw1 = *(const f16x8*)&Wp[(size_t)br1 * KP + kw + bc1];
    if (b2ok) pw2 = *(const f16x8*)&Wp[(size_t)br2 * KP + kw + bc2];
  };

  auto write_lds = [&](int buf) {
    f16x8 pa = ax;
    if constexpr (MODE == 1) pa = ax - ay;
    *(f16x8*)&As[buf][arow][ac] = pa;
    *(f16x8*)&Bs[buf][br0][bc0] = pw0;
    *(f16x8*)&Bs[buf][br1][bc1] = pw1;
    if (b2ok) *(f16x8*)&Bs[buf][br2][bc2] = pw2;
  };

  issue_loads(0);
  write_lds(0);
  issue_loads(1);          // in flight across barrier + compute(0)
  __syncthreads();

  const int row16 = lane & 15, kh = (lane >> 4) * 8;

  for (int ks = 0; ks < KSTEPS; ++ks) {
    const int cur = ks & 1;
    f16x8 af[4], bfr[5];
#pragma unroll
    for (int m = 0; m < 4; ++m)
      af[m] = *(const f16x8*)&As[cur][wr * 64 + m * 16 + row16][kh];
#pragma unroll
    for (int n = 0; n < 5; ++n)
      bfr[n] = *(const f16x8*)&Bs[cur][wc * 80 + n * 16 + row16][kh];
#pragma unroll
    for (int m = 0; m < 4; ++m)
#pragma unroll
      for (int n = 0; n < 5; ++n)
        acc[m][n] = __builtin_amdgcn_mfma_f32_16x16x32_f16(af[m], bfr[n], acc[m][n], 0, 0, 0);

    // write next tile into the other buffer (vmcnt wait lands here, post-MFMA),
    // then immediately issue loads for ks+2 (covered by compute(ks+1))
    if (ks + 1 < KSTEPS) write_lds(cur ^ 1);
    if (ks + 2 < KSTEPS) issue_loads(ks + 2);
    __syncthreads();
  }

  // epilogue: C/D layout col = lane&15, row = (lane>>4)*4 + j  [m89]
  const int rquad = (lane >> 4) * 4;
#pragma unroll
  for (int m = 0; m < 4; ++m) {
#pragma unroll
    for (int n = 0; n < 5; ++n) {
      const int col = wc * 80 + n * 16 + row16;   // < 320 always
#pragma unroll
      for (int j = 0; j < 4; ++j) {
        const int row = mb * BM + wr * 64 + m * 16 + rquad + j;
        float v = acc[m][n][j];
        if constexpr (MODE == 2) {
          if (row < M && col < H)
            out_f32[(size_t)row * H + col] = fmaxf(v + b_o[col], 0.0f);
        } else if constexpr (MODE == 0) {
          if (row < M) {
            size_t o = (size_t)row * HP + col;
            out_inp[o] = (f16)v;
            out_msg[o] = (f16)fmaxf(v, 0.0f);
          }
        } else {
          if (row < M) {
            size_t o = (size_t)row * HP + col;
            float x = v + (float)inp_r[o];
            out_msg[o] = (f16)fmaxf(x, 0.0f);
          }
        }
      }
    }
  }
}

extern "C" void kernel_launch(void* const* d_in, const int* in_sizes, int n_in,
                              void* d_out, int out_size, void* d_ws, size_t ws_size,
                              hipStream_t stream) {
  const float* f_atoms = (const float*)d_in[0];
  const float* f_bonds = (const float*)d_in[1];
  const int*   a2b     = (const int*)d_in[2];
  const int*   b2a     = (const int*)d_in[3];
  const int*   b2revb  = (const int*)d_in[4];
  const float* W_i     = (const float*)d_in[5];
  const float* W_h     = (const float*)d_in[6];
  const float* W_o     = (const float*)d_in[7];
  const float* b_o     = (const float*)d_in[8];
  float* out = (float*)d_out;

  // Workspace budget is tight (448.7 MB known-good, 480.6 MB known-bad).
  // Two lifetime aliases keep total at 448.6 MB:
  //   fb16 <-> amsg      (fb16 dead after gemm0; amsg first written by gather#1)
  //   fa16 <-> msgB[0:]  (fa16 converted AFTER gemm1#2, msgB's last reader)
  char* ws = (char*)d_ws;
  size_t off = 0;
  f16* msgA = (f16*)(ws + off); off += (size_t)NB * HP * 2;   // 128.0 MB
  f16* msgB = (f16*)(ws + off); off += (size_t)NB * HP * 2;   // 128.0 MB
  f16* inp  = (f16*)(ws + off); off += (size_t)NB * HP * 2;   // 128.0 MB
  f16* fb16 = (f16*)(ws + off);                               // alias w/ amsg
  f16* amsg = (f16*)(ws + off); off += (size_t)NB * AFP * 2;  //  64.0 MB
  f16* fa16 = msgB;                                           // alias w/ msgB
  f16* WiP  = (f16*)(ws + off); off += (size_t)NP * 160 * 2;
  f16* WhP  = (f16*)(ws + off); off += (size_t)NP * 320 * 2;
  f16* WoP  = (f16*)(ws + off); off += (size_t)NP * 480 * 2;
  if (off > ws_size) return;  // total ~448.6 MB

  prep_wi<<<(NP * 160 + 255) / 256, 256, 0, stream>>>(W_i, WiP);
  prep_wh<<<(NP * 320 + 255) / 256, 256, 0, stream>>>(W_h, WhP);
  prep_wo<<<(NP * 480 + 255) / 256, 256, 0, stream>>>(W_o, WoP);
  conv_pad_f16<<<(NB * (AFP / 8) + 255) / 256, 256, 0, stream>>>(f_bonds, fb16, NB, BF);

  const int gB = (NB + BM - 1) / BM;   // 1563
  const int gA = (NA + BM - 1) / BM;   // 782
  dim3 gS((NA * (HP / 8) + 255) / 256);

  // inp = fb16 @ W_i ; msgA = relu(inp)
  gemm_kernel<0><<<gB, NTH, 0, stream>>>(fb16, nullptr, nullptr,
                                         nullptr, nullptr, WiP, nullptr, nullptr,
                                         inp, msgA, nullptr);
  // iteration 1: msgB = relu(inp + (amsg[b2a]-msgA[b2revb]) @ W_h)
  gather_sum_kernel<<<gS, 256, 0, stream>>>(msgA, a2b, amsg);   // clobbers fb16 (dead)
  gemm_kernel<1><<<gB, NTH, 0, stream>>>(nullptr, amsg, msgA,
                                         b2a, b2revb, WhP, inp, nullptr,
                                         nullptr, msgB, nullptr);
  // iteration 2: msgA = relu(inp + (amsg[b2a]-msgB[b2revb]) @ W_h)
  gather_sum_kernel<<<gS, 256, 0, stream>>>(msgB, a2b, amsg);
  gemm_kernel<1><<<gB, NTH, 0, stream>>>(nullptr, amsg, msgB,
                                         b2a, b2revb, WhP, inp, nullptr,
                                         nullptr, msgA, nullptr);
  // msgB is now dead -> convert f_atoms into its storage
  conv_pad_f16<<<(NA * (AFP / 8) + 255) / 256, 256, 0, stream>>>(f_atoms, fa16, NA, AF);
  // readout
  gather_sum_kernel<<<gS, 256, 0, stream>>>(msgA, a2b, amsg);
  gemm_kernel<2><<<gA, NTH, 0, stream>>>(fa16, amsg, nullptr,
                                         nullptr, nullptr, WoP, nullptr, b_o,
                                         nullptr, nullptr, out);
}

// Round 13
// 712.449 us; speedup vs baseline: 1.4433x; 1.4433x over previous
//
#include <hip/hip_runtime.h>
#include <hip/hip_fp16.h>

#define NA 100000
#define NB 200000
#define MAXNB 6
#define AF 133
#define BF 147
#define H 300
#define HP 320     // padded fp16 row width for msg/amsg (640B)
#define AFP 160    // padded fp16 row width for f_bonds/f_atoms
#define NP 320     // weight N padding = BN
#define KP_C 480   // uniform K padding: [W_i(160); W_h(320)] / [atoms(160); amsg(320)]
#define BM 128
#define BN 320
#define BK 32
#define NTH 512
#define LDK 40     // LDS row stride (32 + 8 pad)

typedef _Float16 f16;
typedef __attribute__((ext_vector_type(8))) _Float16 f16x8;
typedef __attribute__((ext_vector_type(4))) float f32x4;

// ---- fp32 [M][Ks] -> fp16 [M][160] zero-padded ----------------------------
__global__ void conv_pad_f16(const float* __restrict__ src, f16* __restrict__ dst,
                             int M, int Ks) {
  int idx = blockIdx.x * blockDim.x + threadIdx.x;
  if (idx >= M * (AFP / 8)) return;
  int r = idx / (AFP / 8);
  int c = (idx - r * (AFP / 8)) * 8;
  f16x8 o;
#pragma unroll
  for (int j = 0; j < 8; ++j) {
    int k = c + j;
    o[j] = (k < Ks) ? (f16)src[(size_t)r * Ks + k] : (f16)0.0f;
  }
  *(f16x8*)&dst[(size_t)r * AFP + c] = o;
}

// ---- stacked [W_i; W_h] -> [n][k] fp16, stride KP_C ------------------------
__global__ void prep_w1(const float* __restrict__ Wi, const float* __restrict__ Wh,
                        f16* __restrict__ dst) {
  int idx = blockIdx.x * blockDim.x + threadIdx.x;
  if (idx >= NP * KP_C) return;
  int n = idx / KP_C, k = idx - n * KP_C;
  float v = 0.0f;
  if (n < H) {
    if (k < BF) v = Wi[(size_t)k * H + n];
    else if (k >= AFP && k < AFP + H) v = Wh[(size_t)(k - AFP) * H + n];
  }
  dst[idx] = (f16)v;
}

// ---- W_o remapped for [f_atoms(133->160 pad), amsg(300->320 pad)] ----------
__global__ void prep_wo(const float* __restrict__ src, f16* __restrict__ dst) {
  int idx = blockIdx.x * blockDim.x + threadIdx.x;
  if (idx >= NP * KP_C) return;
  int n = idx / KP_C, k = idx - n * KP_C;
  int ks = -1;
  if (k < AF) ks = k;
  else if (k >= AFP && k < AFP + H) ks = AF + (k - AFP);
  float v = (n < H && ks >= 0) ? src[(size_t)ks * H + n] : 0.0f;
  dst[idx] = (f16)v;
}

// ---- a_msg[a][:] = sum_t msg[a2b[a][t]][:] --------------------------------
__global__ void gather_sum_kernel(const f16* __restrict__ msg,
                                  const int* __restrict__ a2b,
                                  f16* __restrict__ amsg) {
  int idx = blockIdx.x * blockDim.x + threadIdx.x;
  if (idx >= NA * (HP / 8)) return;
  int a = idx / (HP / 8);
  int c = (idx - a * (HP / 8)) * 8;
  const int* nbr = &a2b[(size_t)a * MAXNB];
  float acc[8] = {0.f, 0.f, 0.f, 0.f, 0.f, 0.f, 0.f, 0.f};
#pragma unroll
  for (int t = 0; t < MAXNB; ++t) {
    int r = nbr[t];
    f16x8 v = *(const f16x8*)&msg[(size_t)r * HP + c];
#pragma unroll
    for (int j = 0; j < 8; ++j) acc[j] += (float)v[j];
  }
  f16x8 o;
#pragma unroll
  for (int j = 0; j < 8; ++j) o[j] = (f16)acc[j];
  *(f16x8*)&amsg[(size_t)a * HP + c] = o;
}

// ---- unified GEMM: 128x320 tile, 8 waves (2x4), BK=32, dbuf LDS -----------
// ONE barrier per k-step; loads issued ~1.5 iterations before consumption.
// MODE 0: msg = relu(fb16 @ W_i)                                (K=160)
// MODE 1: msg' = relu([fb16[m], amsg[b2a]-msg[b2revb]] @ [W_i;W_h])  (K=480)
// MODE 2: out = relu([fa16, sum_t msg[a2b[m][t]]] @ W_o + b_o)  (K=480, fused gather)
template <int MODE>
__global__ __launch_bounds__(NTH)
void gemm_kernel(const f16* __restrict__ Afp,    // fb16 (MODE 0/1) / fa16 (MODE 2)
                 const f16* __restrict__ amsg,   // MODE1 only: gathered per-atom sums
                 const f16* __restrict__ msg_in, // MODE1: prev msg; MODE2: final msg
                 const int* __restrict__ b2a,
                 const int* __restrict__ b2revb,
                 const int* __restrict__ a2b,    // MODE2 only
                 const f16* __restrict__ Wp,     // [NP][KP_C]
                 const float* __restrict__ b_o,
                 f16* __restrict__ out_msg,
                 float* __restrict__ out_f32) {
  constexpr int KSTEPS = (MODE == 0) ? 5 : 15;
  constexpr int ASTEPS = 5;                // k-steps sourced from Afp
  constexpr int M = (MODE == 2) ? NA : NB;

  __shared__ f16 As[2][BM][LDK];
  __shared__ f16 Bs[2][BN][LDK];

  const int mb = blockIdx.x;
  const int tid = threadIdx.x;
  const int lane = tid & 63, wid = tid >> 6;
  const int wr = wid >> 2, wc = wid & 3;   // 2 x 4 wave grid

  f32x4 acc[4][5] = {};

  // A staging: 512 8-elem chunks == NTH; thread -> (tid>>2, (tid&3)*8)
  const int arow = tid >> 2;
  const int ac = (tid & 3) * 8;
  const int m_g = mb * BM + arow;
  const int mrow = (m_g < M) ? m_g : 0;  // clamp: OOB rows masked in epilogue

  // B staging: 1280 chunks over 512 threads (3rd chunk partial, tid<256)
  const int bidx2 = tid + 2 * NTH;
  const int br0 = tid >> 2,            bc0 = (tid & 3) * 8;
  const int br1 = (tid + NTH) >> 2,    bc1 = ((tid + NTH) & 3) * 8;
  const int br2 = bidx2 >> 2,          bc2 = (bidx2 & 3) * 8;
  const bool b2ok = bidx2 < BN * 4;

  int ra = 0, rb = 0;
  int n0 = 0, n1 = 0, n2 = 0, n3 = 0, n4 = 0, n5 = 0;
  if constexpr (MODE == 1) { ra = b2a[mrow]; rb = b2revb[mrow]; }
  if constexpr (MODE == 2) {
    const int* p = &a2b[(size_t)mrow * MAXNB];
    n0 = p[0]; n1 = p[1]; n2 = p[2]; n3 = p[3]; n4 = p[4]; n5 = p[5];
  }

  // single staging set: live only from issue to the following write_lds
  f16x8 ax, ay, av0, av1, av2, av3, av4, av5, pw0, pw1, pw2;

  auto issue_loads = [&](int ks) {
    const int kb = ks * BK + ac;
    if constexpr (MODE == 0) {
      ax = *(const f16x8*)&Afp[(size_t)mrow * AFP + kb];
    } else if constexpr (MODE == 1) {
      if (ks < ASTEPS) {
        ax = *(const f16x8*)&Afp[(size_t)mrow * AFP + kb];
      } else {
        const int kk = kb - AFP;
        ax = *(const f16x8*)&amsg[(size_t)ra * HP + kk];
        ay = *(const f16x8*)&msg_in[(size_t)rb * HP + kk];
      }
    } else {
      if (ks < ASTEPS) {
        ax = *(const f16x8*)&Afp[(size_t)mrow * AFP + kb];
      } else {
        const int kk = kb - AFP;
        av0 = *(const f16x8*)&msg_in[(size_t)n0 * HP + kk];
        av1 = *(const f16x8*)&msg_in[(size_t)n1 * HP + kk];
        av2 = *(const f16x8*)&msg_in[(size_t)n2 * HP + kk];
        av3 = *(const f16x8*)&msg_in[(size_t)n3 * HP + kk];
        av4 = *(const f16x8*)&msg_in[(size_t)n4 * HP + kk];
        av5 = *(const f16x8*)&msg_in[(size_t)n5 * HP + kk];
      }
    }
    const int kw = ks * BK;
    pw0 = *(const f16x8*)&Wp[(size_t)br0 * KP_C + kw + bc0];
    pw1 = *(const f16x8*)&Wp[(size_t)br1 * KP_C + kw + bc1];
    if (b2ok) pw2 = *(const f16x8*)&Wp[(size_t)br2 * KP_C + kw + bc2];
  };

  auto write_lds = [&](int buf, int ks) {
    f16x8 pa = ax;
    if constexpr (MODE == 1) {
      if (ks >= ASTEPS) pa = ax - ay;
    }
    if constexpr (MODE == 2) {
      if (ks >= ASTEPS) pa = ((av0 + av1) + (av2 + av3)) + (av4 + av5);
    }
    *(f16x8*)&As[buf][arow][ac] = pa;
    *(f16x8*)&Bs[buf][br0][bc0] = pw0;
    *(f16x8*)&Bs[buf][br1][bc1] = pw1;
    if (b2ok) *(f16x8*)&Bs[buf][br2][bc2] = pw2;
  };

  issue_loads(0);
  write_lds(0, 0);
  issue_loads(1);          // in flight across barrier + compute(0)
  __syncthreads();

  const int row16 = lane & 15, kh = (lane >> 4) * 8;

  for (int ks = 0; ks < KSTEPS; ++ks) {
    const int cur = ks & 1;
    f16x8 af[4], bfr[5];
#pragma unroll
    for (int m = 0; m < 4; ++m)
      af[m] = *(const f16x8*)&As[cur][wr * 64 + m * 16 + row16][kh];
#pragma unroll
    for (int n = 0; n < 5; ++n)
      bfr[n] = *(const f16x8*)&Bs[cur][wc * 80 + n * 16 + row16][kh];
#pragma unroll
    for (int m = 0; m < 4; ++m)
#pragma unroll
      for (int n = 0; n < 5; ++n)
        acc[m][n] = __builtin_amdgcn_mfma_f32_16x16x32_f16(af[m], bfr[n], acc[m][n], 0, 0, 0);

    // write next tile into the other buffer (vmcnt wait lands here, post-MFMA),
    // then immediately issue loads for ks+2 (covered by compute(ks+1))
    if (ks + 1 < KSTEPS) write_lds(cur ^ 1, ks + 1);
    if (ks + 2 < KSTEPS) issue_loads(ks + 2);
    __syncthreads();
  }

  // epilogue: C/D layout col = lane&15, row = (lane>>4)*4 + j  [m89]
  const int rquad = (lane >> 4) * 4;
#pragma unroll
  for (int m = 0; m < 4; ++m) {
#pragma unroll
    for (int n = 0; n < 5; ++n) {
      const int col = wc * 80 + n * 16 + row16;   // < 320 always
#pragma unroll
      for (int j = 0; j < 4; ++j) {
        const int row = mb * BM + wr * 64 + m * 16 + rquad + j;
        float v = acc[m][n][j];
        if constexpr (MODE == 2) {
          if (row < M && col < H)
            out_f32[(size_t)row * H + col] = fmaxf(v + b_o[col], 0.0f);
        } else {
          if (row < M)
            out_msg[(size_t)row * HP + col] = (f16)fmaxf(v, 0.0f);
        }
      }
    }
  }
}

extern "C" void kernel_launch(void* const* d_in, const int* in_sizes, int n_in,
                              void* d_out, int out_size, void* d_ws, size_t ws_size,
                              hipStream_t stream) {
  const float* f_atoms = (const float*)d_in[0];
  const float* f_bonds = (const float*)d_in[1];
  const int*   a2b     = (const int*)d_in[2];
  const int*   b2a     = (const int*)d_in[3];
  const int*   b2revb  = (const int*)d_in[4];
  const float* W_i     = (const float*)d_in[5];
  const float* W_h     = (const float*)d_in[6];
  const float* W_o     = (const float*)d_in[7];
  const float* b_o     = (const float*)d_in[8];
  float* out = (float*)d_out;

  char* ws = (char*)d_ws;
  size_t off = 0;
  f16* msgA = (f16*)(ws + off); off += (size_t)NB * HP * 2;   // 128.0 MB
  f16* msgB = (f16*)(ws + off); off += (size_t)NB * HP * 2;   // 128.0 MB
  f16* amsg = (f16*)(ws + off); off += (size_t)NA * HP * 2;   //  64.0 MB
  f16* fb16 = (f16*)(ws + off); off += (size_t)NB * AFP * 2;  //  64.0 MB
  f16* fa16 = (f16*)(ws + off); off += (size_t)NA * AFP * 2;  //  32.0 MB
  f16* W1P  = (f16*)(ws + off); off += (size_t)NP * KP_C * 2;
  f16* WoP  = (f16*)(ws + off); off += (size_t)NP * KP_C * 2;
  if (off > ws_size) return;  // total ~416.6 MB (known-good budget)

  prep_w1<<<(NP * KP_C + 255) / 256, 256, 0, stream>>>(W_i, W_h, W1P);
  prep_wo<<<(NP * KP_C + 255) / 256, 256, 0, stream>>>(W_o, WoP);
  conv_pad_f16<<<(NB * (AFP / 8) + 255) / 256, 256, 0, stream>>>(f_bonds, fb16, NB, BF);
  conv_pad_f16<<<(NA * (AFP / 8) + 255) / 256, 256, 0, stream>>>(f_atoms, fa16, NA, AF);

  const int gB = (NB + BM - 1) / BM;   // 1563
  const int gA = (NA + BM - 1) / BM;   // 782
  dim3 gS((NA * (HP / 8) + 255) / 256);

  // msgA = relu(fb16 @ W_i)
  gemm_kernel<0><<<gB, NTH, 0, stream>>>(fb16, nullptr, nullptr,
                                         nullptr, nullptr, nullptr, W1P, nullptr,
                                         msgA, nullptr);
  // iteration 1: msgB = relu(inp + (amsg[b2a]-msgA[b2revb]) @ W_h)  [K=480 fused]
  gather_sum_kernel<<<gS, 256, 0, stream>>>(msgA, a2b, amsg);
  gemm_kernel<1><<<gB, NTH, 0, stream>>>(fb16, amsg, msgA,
                                         b2a, b2revb, nullptr, W1P, nullptr,
                                         msgB, nullptr);
  // iteration 2
  gather_sum_kernel<<<gS, 256, 0, stream>>>(msgB, a2b, amsg);
  gemm_kernel<1><<<gB, NTH, 0, stream>>>(fb16, amsg, msgB,
                                         b2a, b2revb, nullptr, W1P, nullptr,
                                         msgA, nullptr);
  // readout: final gather fused into gemm2's A-load (no standalone gather#3)
  gemm_kernel<2><<<gA, NTH, 0, stream>>>(fa16, nullptr, msgA,
                                         nullptr, nullptr, a2b, WoP, b_o,
                                         nullptr, out);
}

// Round 14
// 692.782 us; speedup vs baseline: 1.4843x; 1.0284x over previous
//
#include <hip/hip_runtime.h>
#include <hip/hip_fp16.h>

#define NA 100000
#define NB 200000
#define MAXNB 6
#define AF 133
#define BF 147
#define H 300
#define HP 320     // padded fp16 row width for msg/amsg (640B)
#define AFP 160    // padded fp16 row width for f_bonds/f_atoms
#define NP 320     // weight N padding = BN
#define KP_C 480   // uniform K padding: [W_i(160); W_h(320)] / [atoms(160); amsg(320)]
#define BM 128
#define BN 320
#define BK 32
#define NTH 512
#define LDK 40     // LDS row stride (32 + 8 pad)

typedef _Float16 f16;
typedef __attribute__((ext_vector_type(8))) _Float16 f16x8;
typedef __attribute__((ext_vector_type(4))) float f32x4;

// ---- fp32 [M][Ks] -> fp16 [M][160] zero-padded ----------------------------
__global__ void conv_pad_f16(const float* __restrict__ src, f16* __restrict__ dst,
                             int M, int Ks) {
  int idx = blockIdx.x * blockDim.x + threadIdx.x;
  if (idx >= M * (AFP / 8)) return;
  int r = idx / (AFP / 8);
  int c = (idx - r * (AFP / 8)) * 8;
  f16x8 o;
#pragma unroll
  for (int j = 0; j < 8; ++j) {
    int k = c + j;
    o[j] = (k < Ks) ? (f16)src[(size_t)r * Ks + k] : (f16)0.0f;
  }
  *(f16x8*)&dst[(size_t)r * AFP + c] = o;
}

// ---- stacked [W_i; W_h] -> [n][k] fp16, stride KP_C ------------------------
__global__ void prep_w1(const float* __restrict__ Wi, const float* __restrict__ Wh,
                        f16* __restrict__ dst) {
  int idx = blockIdx.x * blockDim.x + threadIdx.x;
  if (idx >= NP * KP_C) return;
  int n = idx / KP_C, k = idx - n * KP_C;
  float v = 0.0f;
  if (n < H) {
    if (k < BF) v = Wi[(size_t)k * H + n];
    else if (k >= AFP && k < AFP + H) v = Wh[(size_t)(k - AFP) * H + n];
  }
  dst[idx] = (f16)v;
}

// ---- W_o remapped for [f_atoms(133->160 pad), amsg(300->320 pad)] ----------
__global__ void prep_wo(const float* __restrict__ src, f16* __restrict__ dst) {
  int idx = blockIdx.x * blockDim.x + threadIdx.x;
  if (idx >= NP * KP_C) return;
  int n = idx / KP_C, k = idx - n * KP_C;
  int ks = -1;
  if (k < AF) ks = k;
  else if (k >= AFP && k < AFP + H) ks = AF + (k - AFP);
  float v = (n < H && ks >= 0) ? src[(size_t)ks * H + n] : 0.0f;
  dst[idx] = (f16)v;
}

// ---- a_msg[a][:] = sum_t msg[a2b[a][t]][:] --------------------------------
__global__ void gather_sum_kernel(const f16* __restrict__ msg,
                                  const int* __restrict__ a2b,
                                  f16* __restrict__ amsg) {
  int idx = blockIdx.x * blockDim.x + threadIdx.x;
  if (idx >= NA * (HP / 8)) return;
  int a = idx / (HP / 8);
  int c = (idx - a * (HP / 8)) * 8;
  const int* nbr = &a2b[(size_t)a * MAXNB];
  float acc[8] = {0.f, 0.f, 0.f, 0.f, 0.f, 0.f, 0.f, 0.f};
#pragma unroll
  for (int t = 0; t < MAXNB; ++t) {
    int r = nbr[t];
    f16x8 v = *(const f16x8*)&msg[(size_t)r * HP + c];
#pragma unroll
    for (int j = 0; j < 8; ++j) acc[j] += (float)v[j];
  }
  f16x8 o;
#pragma unroll
  for (int j = 0; j < 8; ++j) o[j] = (f16)acc[j];
  *(f16x8*)&amsg[(size_t)a * HP + c] = o;
}

// ---- unified GEMM: 128x320 tile, 8 waves (2x4), BK=32, dbuf LDS -----------
// ONE barrier per k-step. A-staging is 2-deep (two alternating register sets,
// issued two compute-phases before consumption) for MODE 0/1; MODE 2 keeps
// the 1-deep schedule (6-row gather set would cost +24 VGPRs).
// MODE 0: msg = relu(fb16 @ W_i)                                (K=160)
// MODE 1: msg' = relu([fb16[m], amsg[b2a]-msg[b2revb]] @ [W_i;W_h])  (K=480)
// MODE 2: out = relu([fa16, sum_t msg[a2b[m][t]]] @ W_o + b_o)  (K=480, fused gather)
template <int MODE>
__global__ __launch_bounds__(NTH)
void gemm_kernel(const f16* __restrict__ Afp,    // fb16 (MODE 0/1) / fa16 (MODE 2)
                 const f16* __restrict__ amsg,   // MODE1 only: gathered per-atom sums
                 const f16* __restrict__ msg_in, // MODE1: prev msg; MODE2: final msg
                 const int* __restrict__ b2a,
                 const int* __restrict__ b2revb,
                 const int* __restrict__ a2b,    // MODE2 only
                 const f16* __restrict__ Wp,     // [NP][KP_C]
                 const float* __restrict__ b_o,
                 f16* __restrict__ out_msg,
                 float* __restrict__ out_f32) {
  constexpr int KSTEPS = (MODE == 0) ? 5 : 15;
  constexpr int ASTEPS = 5;                // k-steps sourced from Afp
  constexpr int M = (MODE == 2) ? NA : NB;
  constexpr bool DEEP = (MODE != 2);       // 2-deep A-issue placement

  __shared__ f16 As[2][BM][LDK];
  __shared__ f16 Bs[2][BN][LDK];

  const int mb = blockIdx.x;
  const int tid = threadIdx.x;
  const int lane = tid & 63, wid = tid >> 6;
  const int wr = wid >> 2, wc = wid & 3;   // 2 x 4 wave grid

  f32x4 acc[4][5] = {};

  // A staging: 512 8-elem chunks == NTH; thread -> (tid>>2, (tid&3)*8)
  const int arow = tid >> 2;
  const int ac = (tid & 3) * 8;
  const int m_g = mb * BM + arow;
  const int mrow = (m_g < M) ? m_g : 0;  // clamp: OOB rows masked in epilogue

  // B staging: 1280 chunks over 512 threads (3rd chunk partial, tid<256)
  const int bidx2 = tid + 2 * NTH;
  const int br0 = tid >> 2,            bc0 = (tid & 3) * 8;
  const int br1 = (tid + NTH) >> 2,    bc1 = ((tid + NTH) & 3) * 8;
  const int br2 = bidx2 >> 2,          bc2 = (bidx2 & 3) * 8;
  const bool b2ok = bidx2 < BN * 4;

  int ra = 0, rb = 0;
  int n0 = 0, n1 = 0, n2 = 0, n3 = 0, n4 = 0, n5 = 0;
  if constexpr (MODE == 1) { ra = b2a[mrow]; rb = b2revb[mrow]; }
  if constexpr (MODE == 2) {
    const int* p = &a2b[(size_t)mrow * MAXNB];
    n0 = p[0]; n1 = p[1]; n2 = p[2]; n3 = p[3]; n4 = p[4]; n5 = p[5];
  }

  // two alternating A-staging sets (static names, rule #20); one B set
  f16x8 axA, ayA, avA[6];
  f16x8 axB, ayB, avB[6];
  f16x8 pw0, pw1, pw2;

  auto issueA = [&](int ks, f16x8& ax, f16x8& ay, f16x8 (&av)[6]) {
    const int kb = ks * BK + ac;
    if constexpr (MODE == 0) {
      ax = *(const f16x8*)&Afp[(size_t)mrow * AFP + kb];
    } else if constexpr (MODE == 1) {
      if (ks < ASTEPS) {
        ax = *(const f16x8*)&Afp[(size_t)mrow * AFP + kb];
      } else {
        const int kk = kb - AFP;
        ax = *(const f16x8*)&amsg[(size_t)ra * HP + kk];
        ay = *(const f16x8*)&msg_in[(size_t)rb * HP + kk];
      }
    } else {
      if (ks < ASTEPS) {
        ax = *(const f16x8*)&Afp[(size_t)mrow * AFP + kb];
      } else {
        const int kk = kb - AFP;
        av[0] = *(const f16x8*)&msg_in[(size_t)n0 * HP + kk];
        av[1] = *(const f16x8*)&msg_in[(size_t)n1 * HP + kk];
        av[2] = *(const f16x8*)&msg_in[(size_t)n2 * HP + kk];
        av[3] = *(const f16x8*)&msg_in[(size_t)n3 * HP + kk];
        av[4] = *(const f16x8*)&msg_in[(size_t)n4 * HP + kk];
        av[5] = *(const f16x8*)&msg_in[(size_t)n5 * HP + kk];
      }
    }
  };

  auto issueB = [&](int ks) {
    const int kw = ks * BK;
    pw0 = *(const f16x8*)&Wp[(size_t)br0 * KP_C + kw + bc0];
    pw1 = *(const f16x8*)&Wp[(size_t)br1 * KP_C + kw + bc1];
    if (b2ok) pw2 = *(const f16x8*)&Wp[(size_t)br2 * KP_C + kw + bc2];
  };

  auto write_lds = [&](int buf, int ks, f16x8& ax, f16x8& ay, f16x8 (&av)[6]) {
    f16x8 pa = ax;
    if constexpr (MODE == 1) {
      if (ks >= ASTEPS) pa = ax - ay;
    }
    if constexpr (MODE == 2) {
      if (ks >= ASTEPS) pa = ((av[0] + av[1]) + (av[2] + av[3])) + (av[4] + av[5]);
    }
    *(f16x8*)&As[buf][arow][ac] = pa;
    *(f16x8*)&Bs[buf][br0][bc0] = pw0;
    *(f16x8*)&Bs[buf][br1][bc1] = pw1;
    if (b2ok) *(f16x8*)&Bs[buf][br2][bc2] = pw2;
  };

  const int row16 = lane & 15, kh = (lane >> 4) * 8;

  auto compute = [&](int buf) {
    f16x8 af[4], bfr[5];
#pragma unroll
    for (int m = 0; m < 4; ++m)
      af[m] = *(const f16x8*)&As[buf][wr * 64 + m * 16 + row16][kh];
#pragma unroll
    for (int n = 0; n < 5; ++n)
      bfr[n] = *(const f16x8*)&Bs[buf][wc * 80 + n * 16 + row16][kh];
#pragma unroll
    for (int m = 0; m < 4; ++m)
#pragma unroll
      for (int n = 0; n < 5; ++n)
        acc[m][n] = __builtin_amdgcn_mfma_f32_16x16x32_f16(af[m], bfr[n], acc[m][n], 0, 0, 0);
  };

  // prologue
  issueA(0, axA, ayA, avA); issueB(0);
  write_lds(0, 0, axA, ayA, avA);
  issueA(1, axB, ayB, avB); issueB(1);
  __syncthreads();

  for (int ks = 0; ks < KSTEPS; ks += 2) {
    // ---- even step: computes global step ks in buf0 ----
    if (DEEP && ks + 2 < KSTEPS) issueA(ks + 2, axA, ayA, avA);
    compute(0);
    if (ks + 1 < KSTEPS) write_lds(1, ks + 1, axB, ayB, avB);
    if (!DEEP && ks + 2 < KSTEPS) issueA(ks + 2, axA, ayA, avA);
    if (ks + 2 < KSTEPS) issueB(ks + 2);
    __syncthreads();
    // ---- odd step: computes global step ks+1 in buf1 ----
    if (ks + 1 < KSTEPS) {
      if (DEEP && ks + 3 < KSTEPS) issueA(ks + 3, axB, ayB, avB);
      compute(1);
      if (ks + 2 < KSTEPS) write_lds(0, ks + 2, axA, ayA, avA);
      if (!DEEP && ks + 3 < KSTEPS) issueA(ks + 3, axB, ayB, avB);
      if (ks + 3 < KSTEPS) issueB(ks + 3);
      __syncthreads();
    }
  }

  // epilogue: C/D layout col = lane&15, row = (lane>>4)*4 + j  [m89]
  const int rquad = (lane >> 4) * 4;
#pragma unroll
  for (int m = 0; m < 4; ++m) {
#pragma unroll
    for (int n = 0; n < 5; ++n) {
      const int col = wc * 80 + n * 16 + row16;   // < 320 always
#pragma unroll
      for (int j = 0; j < 4; ++j) {
        const int row = mb * BM + wr * 64 + m * 16 + rquad + j;
        float v = acc[m][n][j];
        if constexpr (MODE == 2) {
          if (row < M && col < H)
            out_f32[(size_t)row * H + col] = fmaxf(v + b_o[col], 0.0f);
        } else {
          if (row < M)
            out_msg[(size_t)row * HP + col] = (f16)fmaxf(v, 0.0f);
        }
      }
    }
  }
}

extern "C" void kernel_launch(void* const* d_in, const int* in_sizes, int n_in,
                              void* d_out, int out_size, void* d_ws, size_t ws_size,
                              hipStream_t stream) {
  const float* f_atoms = (const float*)d_in[0];
  const float* f_bonds = (const float*)d_in[1];
  const int*   a2b     = (const int*)d_in[2];
  const int*   b2a     = (const int*)d_in[3];
  const int*   b2revb  = (const int*)d_in[4];
  const float* W_i     = (const float*)d_in[5];
  const float* W_h     = (const float*)d_in[6];
  const float* W_o     = (const float*)d_in[7];
  const float* b_o     = (const float*)d_in[8];
  float* out = (float*)d_out;

  char* ws = (char*)d_ws;
  size_t off = 0;
  f16* msgA = (f16*)(ws + off); off += (size_t)NB * HP * 2;   // 128.0 MB
  f16* msgB = (f16*)(ws + off); off += (size_t)NB * HP * 2;   // 128.0 MB
  f16* amsg = (f16*)(ws + off); off += (size_t)NA * HP * 2;   //  64.0 MB
  f16* fb16 = (f16*)(ws + off); off += (size_t)NB * AFP * 2;  //  64.0 MB
  f16* fa16 = (f16*)(ws + off); off += (size_t)NA * AFP * 2;  //  32.0 MB
  f16* W1P  = (f16*)(ws + off); off += (size_t)NP * KP_C * 2;
  f16* WoP  = (f16*)(ws + off); off += (size_t)NP * KP_C * 2;
  if (off > ws_size) return;  // total ~416.6 MB (known-good budget)

  prep_w1<<<(NP * KP_C + 255) / 256, 256, 0, stream>>>(W_i, W_h, W1P);
  prep_wo<<<(NP * KP_C + 255) / 256, 256, 0, stream>>>(W_o, WoP);
  conv_pad_f16<<<(NB * (AFP / 8) + 255) / 256, 256, 0, stream>>>(f_bonds, fb16, NB, BF);
  conv_pad_f16<<<(NA * (AFP / 8) + 255) / 256, 256, 0, stream>>>(f_atoms, fa16, NA, AF);

  const int gB = (NB + BM - 1) / BM;   // 1563
  const int gA = (NA + BM - 1) / BM;   // 782
  dim3 gS((NA * (HP / 8) + 255) / 256);

  // msgA = relu(fb16 @ W_i)
  gemm_kernel<0><<<gB, NTH, 0, stream>>>(fb16, nullptr, nullptr,
                                         nullptr, nullptr, nullptr, W1P, nullptr,
                                         msgA, nullptr);
  // iteration 1: msgB = relu(inp + (amsg[b2a]-msgA[b2revb]) @ W_h)  [K=480 fused]
  gather_sum_kernel<<<gS, 256, 0, stream>>>(msgA, a2b, amsg);
  gemm_kernel<1><<<gB, NTH, 0, stream>>>(fb16, amsg, msgA,
                                         b2a, b2revb, nullptr, W1P, nullptr,
                                         msgB, nullptr);
  // iteration 2
  gather_sum_kernel<<<gS, 256, 0, stream>>>(msgB, a2b, amsg);
  gemm_kernel<1><<<gB, NTH, 0, stream>>>(fb16, amsg, msgB,
                                         b2a, b2revb, nullptr, W1P, nullptr,
                                         msgA, nullptr);
  // readout: final gather fused into gemm2's A-load (no standalone gather#3)
  gemm_kernel<2><<<gA, NTH, 0, stream>>>(fa16, nullptr, msgA,
                                         nullptr, nullptr, a2b, WoP, b_o,
                                         nullptr, out);
}

// Round 15
// 687.605 us; speedup vs baseline: 1.4955x; 1.0075x over previous
//
#include <hip/hip_runtime.h>
#include <hip/hip_fp16.h>

#define NA 100000
#define NB 200000
#define MAXNB 6
#define AF 133
#define BF 147
#define H 300
#define HP 320     // padded fp16 row width for msg/amsg (640B)
#define AFP 160    // padded fp16 row width for f_bonds/f_atoms
#define NP 320     // weight N padding = BN
#define KP_C 480   // uniform K padding: [W_i(160); W_h(320)] / [atoms(160); amsg(320)]
#define BM 128
#define BN 320
#define BK 32
#define NTH 512
#define LDK 40     // LDS row stride (32 + 8 pad)

typedef _Float16 f16;
typedef __attribute__((ext_vector_type(8))) _Float16 f16x8;
typedef __attribute__((ext_vector_type(4))) float f32x4;

// ---- fp32 [M][Ks] -> fp16 [M][160] zero-padded ----------------------------
__global__ void conv_pad_f16(const float* __restrict__ src, f16* __restrict__ dst,
                             int M, int Ks) {
  int idx = blockIdx.x * blockDim.x + threadIdx.x;
  if (idx >= M * (AFP / 8)) return;
  int r = idx / (AFP / 8);
  int c = (idx - r * (AFP / 8)) * 8;
  f16x8 o;
#pragma unroll
  for (int j = 0; j < 8; ++j) {
    int k = c + j;
    o[j] = (k < Ks) ? (f16)src[(size_t)r * Ks + k] : (f16)0.0f;
  }
  *(f16x8*)&dst[(size_t)r * AFP + c] = o;
}

// ---- stacked [W_i; W_h] -> [n][k] fp16, stride KP_C ------------------------
__global__ void prep_w1(const float* __restrict__ Wi, const float* __restrict__ Wh,
                        f16* __restrict__ dst) {
  int idx = blockIdx.x * blockDim.x + threadIdx.x;
  if (idx >= NP * KP_C) return;
  int n = idx / KP_C, k = idx - n * KP_C;
  float v = 0.0f;
  if (n < H) {
    if (k < BF) v = Wi[(size_t)k * H + n];
    else if (k >= AFP && k < AFP + H) v = Wh[(size_t)(k - AFP) * H + n];
  }
  dst[idx] = (f16)v;
}

// ---- W_o remapped for [f_atoms(133->160 pad), amsg(300->320 pad)] ----------
__global__ void prep_wo(const float* __restrict__ src, f16* __restrict__ dst) {
  int idx = blockIdx.x * blockDim.x + threadIdx.x;
  if (idx >= NP * KP_C) return;
  int n = idx / KP_C, k = idx - n * KP_C;
  int ks = -1;
  if (k < AF) ks = k;
  else if (k >= AFP && k < AFP + H) ks = AF + (k - AFP);
  float v = (n < H && ks >= 0) ? src[(size_t)ks * H + n] : 0.0f;
  dst[idx] = (f16)v;
}

// ---- a_msg[a][:] = sum_t msg[a2b[a][t]][:] --------------------------------
__global__ void gather_sum_kernel(const f16* __restrict__ msg,
                                  const int* __restrict__ a2b,
                                  f16* __restrict__ amsg) {
  int idx = blockIdx.x * blockDim.x + threadIdx.x;
  if (idx >= NA * (HP / 8)) return;
  int a = idx / (HP / 8);
  int c = (idx - a * (HP / 8)) * 8;
  const int* nbr = &a2b[(size_t)a * MAXNB];
  float acc[8] = {0.f, 0.f, 0.f, 0.f, 0.f, 0.f, 0.f, 0.f};
#pragma unroll
  for (int t = 0; t < MAXNB; ++t) {
    int r = nbr[t];
    f16x8 v = *(const f16x8*)&msg[(size_t)r * HP + c];
#pragma unroll
    for (int j = 0; j < 8; ++j) acc[j] += (float)v[j];
  }
  f16x8 o;
#pragma unroll
  for (int j = 0; j < 8; ++j) o[j] = (f16)acc[j];
  *(f16x8*)&amsg[(size_t)a * HP + c] = o;
}

// ---- unified GEMM: 128x320 tile, 8 waves (2x4), BK=32, dbuf LDS -----------
// ONE barrier per k-step. A-staging is 2-deep in ALL modes: two alternating
// register sets, issued two compute-phases before consumption (the issue sits
// at the top of the iteration, so HBM-random latency is covered by a full
// compute+write+barrier+compute window).
// MODE 0: msg = relu(fb16 @ W_i)                                (K=160)
// MODE 1: msg' = relu([fb16[m], amsg[b2a]-msg[b2revb]] @ [W_i;W_h])  (K=480)
// MODE 2: out = relu([fa16, sum_t msg[a2b[m][t]]] @ W_o + b_o)  (K=480, fused gather)
template <int MODE>
__global__ __launch_bounds__(NTH)
void gemm_kernel(const f16* __restrict__ Afp,    // fb16 (MODE 0/1) / fa16 (MODE 2)
                 const f16* __restrict__ amsg,   // MODE1 only: gathered per-atom sums
                 const f16* __restrict__ msg_in, // MODE1: prev msg; MODE2: final msg
                 const int* __restrict__ b2a,
                 const int* __restrict__ b2revb,
                 const int* __restrict__ a2b,    // MODE2 only
                 const f16* __restrict__ Wp,     // [NP][KP_C]
                 const float* __restrict__ b_o,
                 f16* __restrict__ out_msg,
                 float* __restrict__ out_f32) {
  constexpr int KSTEPS = (MODE == 0) ? 5 : 15;
  constexpr int ASTEPS = 5;                // k-steps sourced from Afp
  constexpr int M = (MODE == 2) ? NA : NB;

  __shared__ f16 As[2][BM][LDK];
  __shared__ f16 Bs[2][BN][LDK];

  const int mb = blockIdx.x;
  const int tid = threadIdx.x;
  const int lane = tid & 63, wid = tid >> 6;
  const int wr = wid >> 2, wc = wid & 3;   // 2 x 4 wave grid

  f32x4 acc[4][5] = {};

  // A staging: 512 8-elem chunks == NTH; thread -> (tid>>2, (tid&3)*8)
  const int arow = tid >> 2;
  const int ac = (tid & 3) * 8;
  const int m_g = mb * BM + arow;
  const int mrow = (m_g < M) ? m_g : 0;  // clamp: OOB rows masked in epilogue

  // B staging: 1280 chunks over 512 threads (3rd chunk partial, tid<256)
  const int bidx2 = tid + 2 * NTH;
  const int br0 = tid >> 2,            bc0 = (tid & 3) * 8;
  const int br1 = (tid + NTH) >> 2,    bc1 = ((tid + NTH) & 3) * 8;
  const int br2 = bidx2 >> 2,          bc2 = (bidx2 & 3) * 8;
  const bool b2ok = bidx2 < BN * 4;

  int ra = 0, rb = 0;
  int n0 = 0, n1 = 0, n2 = 0, n3 = 0, n4 = 0, n5 = 0;
  if constexpr (MODE == 1) { ra = b2a[mrow]; rb = b2revb[mrow]; }
  if constexpr (MODE == 2) {
    const int* p = &a2b[(size_t)mrow * MAXNB];
    n0 = p[0]; n1 = p[1]; n2 = p[2]; n3 = p[3]; n4 = p[4]; n5 = p[5];
  }

  // two alternating A-staging sets (static names, rule #20); one B set
  f16x8 axA, ayA, avA[6];
  f16x8 axB, ayB, avB[6];
  f16x8 pw0, pw1, pw2;

  auto issueA = [&](int ks, f16x8& ax, f16x8& ay, f16x8 (&av)[6]) {
    const int kb = ks * BK + ac;
    if constexpr (MODE == 0) {
      ax = *(const f16x8*)&Afp[(size_t)mrow * AFP + kb];
    } else if constexpr (MODE == 1) {
      if (ks < ASTEPS) {
        ax = *(const f16x8*)&Afp[(size_t)mrow * AFP + kb];
      } else {
        const int kk = kb - AFP;
        ax = *(const f16x8*)&amsg[(size_t)ra * HP + kk];
        ay = *(const f16x8*)&msg_in[(size_t)rb * HP + kk];
      }
    } else {
      if (ks < ASTEPS) {
        ax = *(const f16x8*)&Afp[(size_t)mrow * AFP + kb];
      } else {
        const int kk = kb - AFP;
        av[0] = *(const f16x8*)&msg_in[(size_t)n0 * HP + kk];
        av[1] = *(const f16x8*)&msg_in[(size_t)n1 * HP + kk];
        av[2] = *(const f16x8*)&msg_in[(size_t)n2 * HP + kk];
        av[3] = *(const f16x8*)&msg_in[(size_t)n3 * HP + kk];
        av[4] = *(const f16x8*)&msg_in[(size_t)n4 * HP + kk];
        av[5] = *(const f16x8*)&msg_in[(size_t)n5 * HP + kk];
      }
    }
  };

  auto issueB = [&](int ks) {
    const int kw = ks * BK;
    pw0 = *(const f16x8*)&Wp[(size_t)br0 * KP_C + kw + bc0];
    pw1 = *(const f16x8*)&Wp[(size_t)br1 * KP_C + kw + bc1];
    if (b2ok) pw2 = *(const f16x8*)&Wp[(size_t)br2 * KP_C + kw + bc2];
  };

  auto write_lds = [&](int buf, int ks, f16x8& ax, f16x8& ay, f16x8 (&av)[6]) {
    f16x8 pa = ax;
    if constexpr (MODE == 1) {
      if (ks >= ASTEPS) pa = ax - ay;
    }
    if constexpr (MODE == 2) {
      if (ks >= ASTEPS) pa = ((av[0] + av[1]) + (av[2] + av[3])) + (av[4] + av[5]);
    }
    *(f16x8*)&As[buf][arow][ac] = pa;
    *(f16x8*)&Bs[buf][br0][bc0] = pw0;
    *(f16x8*)&Bs[buf][br1][bc1] = pw1;
    if (b2ok) *(f16x8*)&Bs[buf][br2][bc2] = pw2;
  };

  const int row16 = lane & 15, kh = (lane >> 4) * 8;

  auto compute = [&](int buf) {
    f16x8 af[4], bfr[5];
#pragma unroll
    for (int m = 0; m < 4; ++m)
      af[m] = *(const f16x8*)&As[buf][wr * 64 + m * 16 + row16][kh];
#pragma unroll
    for (int n = 0; n < 5; ++n)
      bfr[n] = *(const f16x8*)&Bs[buf][wc * 80 + n * 16 + row16][kh];
#pragma unroll
    for (int m = 0; m < 4; ++m)
#pragma unroll
      for (int n = 0; n < 5; ++n)
        acc[m][n] = __builtin_amdgcn_mfma_f32_16x16x32_f16(af[m], bfr[n], acc[m][n], 0, 0, 0);
  };

  // prologue
  issueA(0, axA, ayA, avA); issueB(0);
  write_lds(0, 0, axA, ayA, avA);
  issueA(1, axB, ayB, avB); issueB(1);
  __syncthreads();

  for (int ks = 0; ks < KSTEPS; ks += 2) {
    // ---- even step: computes global step ks in buf0 ----
    if (ks + 2 < KSTEPS) issueA(ks + 2, axA, ayA, avA);   // 2-deep issue
    compute(0);
    if (ks + 1 < KSTEPS) write_lds(1, ks + 1, axB, ayB, avB);
    if (ks + 2 < KSTEPS) issueB(ks + 2);
    __syncthreads();
    // ---- odd step: computes global step ks+1 in buf1 ----
    if (ks + 1 < KSTEPS) {
      if (ks + 3 < KSTEPS) issueA(ks + 3, axB, ayB, avB); // 2-deep issue
      compute(1);
      if (ks + 2 < KSTEPS) write_lds(0, ks + 2, axA, ayA, avA);
      if (ks + 3 < KSTEPS) issueB(ks + 3);
      __syncthreads();
    }
  }

  // epilogue: C/D layout col = lane&15, row = (lane>>4)*4 + j  [m89]
  const int rquad = (lane >> 4) * 4;
#pragma unroll
  for (int m = 0; m < 4; ++m) {
#pragma unroll
    for (int n = 0; n < 5; ++n) {
      const int col = wc * 80 + n * 16 + row16;   // < 320 always
#pragma unroll
      for (int j = 0; j < 4; ++j) {
        const int row = mb * BM + wr * 64 + m * 16 + rquad + j;
        float v = acc[m][n][j];
        if constexpr (MODE == 2) {
          if (row < M && col < H)
            out_f32[(size_t)row * H + col] = fmaxf(v + b_o[col], 0.0f);
        } else {
          if (row < M)
            out_msg[(size_t)row * HP + col] = (f16)fmaxf(v, 0.0f);
        }
      }
    }
  }
}

extern "C" void kernel_launch(void* const* d_in, const int* in_sizes, int n_in,
                              void* d_out, int out_size, void* d_ws, size_t ws_size,
                              hipStream_t stream) {
  const float* f_atoms = (const float*)d_in[0];
  const float* f_bonds = (const float*)d_in[1];
  const int*   a2b     = (const int*)d_in[2];
  const int*   b2a     = (const int*)d_in[3];
  const int*   b2revb  = (const int*)d_in[4];
  const float* W_i     = (const float*)d_in[5];
  const float* W_h     = (const float*)d_in[6];
  const float* W_o     = (const float*)d_in[7];
  const float* b_o     = (const float*)d_in[8];
  float* out = (float*)d_out;

  char* ws = (char*)d_ws;
  size_t off = 0;
  f16* msgA = (f16*)(ws + off); off += (size_t)NB * HP * 2;   // 128.0 MB
  f16* msgB = (f16*)(ws + off); off += (size_t)NB * HP * 2;   // 128.0 MB
  f16* amsg = (f16*)(ws + off); off += (size_t)NA * HP * 2;   //  64.0 MB
  f16* fb16 = (f16*)(ws + off); off += (size_t)NB * AFP * 2;  //  64.0 MB
  f16* fa16 = (f16*)(ws + off); off += (size_t)NA * AFP * 2;  //  32.0 MB
  f16* W1P  = (f16*)(ws + off); off += (size_t)NP * KP_C * 2;
  f16* WoP  = (f16*)(ws + off); off += (size_t)NP * KP_C * 2;
  if (off > ws_size) return;  // total ~416.6 MB (known-good budget)

  prep_w1<<<(NP * KP_C + 255) / 256, 256, 0, stream>>>(W_i, W_h, W1P);
  prep_wo<<<(NP * KP_C + 255) / 256, 256, 0, stream>>>(W_o, WoP);
  conv_pad_f16<<<(NB * (AFP / 8) + 255) / 256, 256, 0, stream>>>(f_bonds, fb16, NB, BF);
  conv_pad_f16<<<(NA * (AFP / 8) + 255) / 256, 256, 0, stream>>>(f_atoms, fa16, NA, AF);

  const int gB = (NB + BM - 1) / BM;   // 1563
  const int gA = (NA + BM - 1) / BM;   // 782
  dim3 gS((NA * (HP / 8) + 255) / 256);

  // msgA = relu(fb16 @ W_i)
  gemm_kernel<0><<<gB, NTH, 0, stream>>>(fb16, nullptr, nullptr,
                                         nullptr, nullptr, nullptr, W1P, nullptr,
                                         msgA, nullptr);
  // iteration 1: msgB = relu(inp + (amsg[b2a]-msgA[b2revb]) @ W_h)  [K=480 fused]
  gather_sum_kernel<<<gS, 256, 0, stream>>>(msgA, a2b, amsg);
  gemm_kernel<1><<<gB, NTH, 0, stream>>>(fb16, amsg, msgA,
                                         b2a, b2revb, nullptr, W1P, nullptr,
                                         msgB, nullptr);
  // iteration 2
  gather_sum_kernel<<<gS, 256, 0, stream>>>(msgB, a2b, amsg);
  gemm_kernel<1><<<gB, NTH, 0, stream>>>(fb16, amsg, msgB,
                                         b2a, b2revb, nullptr, W1P, nullptr,
                                         msgA, nullptr);
  // readout: final gather fused into gemm2's A-load (no standalone gather#3)
  gemm_kernel<2><<<gA, NTH, 0, stream>>>(fa16, nullptr, msgA,
                                         nullptr, nullptr, a2b, WoP, b_o,
                                         nullptr, out);
}